// Round 2
// baseline (638.591 us; speedup 1.0000x reference)
//
#include <hip/hip_runtime.h>
#include <math.h>

#define HIDDEN 1024
#define NEXP   64
#define MT     64     // tokens per block (single wave)
#define KC     32     // k per chunk

// ws layout (floats)
#define WT_OFF 0        // Wt[k][e] : 1024*64
#define QL_OFF 65536    // qry_logits[b][e] : 8*64

// out layout (floats): topk_scores, topk_idx, gate_scores, gate_logits
#define OUT_TKS 0
#define OUT_TKI 147456
#define OUT_GS  294912
#define OUT_GL  5013504

// blocks 0..255: transpose W_vis -> Wt[k][e]; blocks 256..263: qry logits
__global__ __launch_bounds__(256) void prep_kernel(
    const float* __restrict__ query_emb, const float* __restrict__ W_gate,
    float* __restrict__ ws) {
  const int bid = blockIdx.x;
  const int tid = threadIdx.x;
  if (bid < 256) {
    const int idx = bid * 256 + tid;       // 0..65535
    const int k = idx >> 6, e = idx & 63;
    ws[WT_OFF + idx] = W_gate[e * 2048 + k];
  } else {
    const int b = bid - 256;               // 0..7
    const int e = tid >> 2, q = tid & 3;   // expert, quarter of K
    const float* qp = query_emb + b * 1024 + q * 256;
    const float* wp = W_gate + e * 2048 + 1024 + q * 256;
    float s = 0.f;
    #pragma unroll 4
    for (int j = 0; j < 256; j += 4) {
      const float4 a = *(const float4*)(qp + j);
      const float4 w = *(const float4*)(wp + j);
      s += a.x * w.x + a.y * w.y + a.z * w.z + a.w * w.w;
    }
    s += __shfl_xor(s, 1);
    s += __shfl_xor(s, 2);
    if (q == 0) ws[QL_OFF + b * 64 + e] = s;
  }
}

// Single-wave workgroup: 64 threads own 64 tokens x 64 experts, 8x8 per thread.
// No barriers; wave stages its own LDS tiles; ~10 independent waves/CU.
__global__ __launch_bounds__(64, 2) void router_main(
    const float* __restrict__ vis, const float* __restrict__ ws,
    float* __restrict__ out) {
  // As: k-major swizzled: element (k,t) at word k*64 + (t ^ (k & 28))
  __shared__ __align__(16) float As[KC * 64];
  __shared__ __align__(16) float Ws[KC * 64];   // [k][e] linear
  const int tid = threadIdx.x;     // 0..63, one wave
  const int ec  = tid & 7;         // expert col: experts ec*8..ec*8+7
  const int r   = tid >> 3;        // token row:  tokens  r*8..r*8+7
  const int k4  = tid & 7;         // staging k-group (4 k's each)
  const long base = (long)blockIdx.x * MT;
  const float* Wt = ws + WT_OFF;
  const float* arow = vis + base * HIDDEN;

  float acc[8][8] = {};

  float4 pfa[8];                   // A prefetch: 8 rows x 16B
  float4 pfb[8];                   // B prefetch: 8 KB chunk / 64 lanes
  #pragma unroll
  for (int p = 0; p < 8; ++p)
    pfa[p] = *(const float4*)(arow + (p * 8 + r) * HIDDEN + k4 * 4);
  #pragma unroll
  for (int i = 0; i < 8; ++i)
    pfb[i] = *(const float4*)(Wt + i * 256 + tid * 4);

  for (int c = 0; c < 32; ++c) {
    // ---- stage chunk c into LDS from prefetch regs ----
    #pragma unroll
    for (int p = 0; p < 8; ++p) {
      const int t = p * 8 + r;
      const int w0 = (k4 * 4) * 64 + (t ^ (k4 * 4));
      As[w0]       = pfa[p].x;
      As[w0 + 64]  = pfa[p].y;
      As[w0 + 128] = pfa[p].z;
      As[w0 + 192] = pfa[p].w;
    }
    #pragma unroll
    for (int i = 0; i < 8; ++i)
      *(float4*)&Ws[i * 256 + tid * 4] = pfb[i];

    // ---- prefetch chunk c+1 (in flight across the compute loop) ----
    const int kn = (c < 31) ? (c + 1) * KC : 0;
    #pragma unroll
    for (int p = 0; p < 8; ++p)
      pfa[p] = *(const float4*)(arow + (p * 8 + r) * HIDDEN + kn + k4 * 4);
    #pragma unroll
    for (int i = 0; i < 8; ++i)
      pfb[i] = *(const float4*)(Wt + kn * 64 + i * 256 + tid * 4);

    // ---- compute chunk c: 64 FMA per k from 4 ds_read_b128 ----
    #pragma unroll 4
    for (int k = 0; k < KC; ++k) {
      const int sw = k & 28;
      const int ai = k * 64 + ((r * 8) ^ sw);
      const float4 a0 = *(const float4*)&As[ai];
      const float4 a1 = *(const float4*)&As[ai ^ 4];
      const float4 b0 = *(const float4*)&Ws[k * 64 + ec * 8];
      const float4 b1 = *(const float4*)&Ws[k * 64 + ec * 8 + 4];
      const float av[8] = {a0.x, a0.y, a0.z, a0.w, a1.x, a1.y, a1.z, a1.w};
      const float bv[8] = {b0.x, b0.y, b0.z, b0.w, b1.x, b1.y, b1.z, b1.w};
      #pragma unroll
      for (int i = 0; i < 8; ++i)
        #pragma unroll
        for (int j = 0; j < 8; ++j)
          acc[i][j] += av[i] * bv[j];
    }
  }

  // ---- epilogue: qry add, logits, softmax, top-2 ----
  const int bq = blockIdx.x / 144;   // 9216 tokens per query row; 144 blocks each
  const float4 qv0 = *(const float4*)(ws + QL_OFF + bq * 64 + ec * 8);
  const float4 qv1 = *(const float4*)(ws + QL_OFF + bq * 64 + ec * 8 + 4);
  const float ql[8] = {qv0.x, qv0.y, qv0.z, qv0.w, qv1.x, qv1.y, qv1.z, qv1.w};

  float* out_tks = out + OUT_TKS;
  float* out_tki = out + OUT_TKI;
  float* out_gs  = out + OUT_GS;
  float* out_gl  = out + OUT_GL;

  #pragma unroll
  for (int i = 0; i < 8; ++i) {
    const long tok = base + r * 8 + i;
    float l[8];
    #pragma unroll
    for (int j = 0; j < 8; ++j) l[j] = acc[i][j] + ql[j];
    *(float4*)(out_gl + tok * 64 + ec * 8)     = make_float4(l[0], l[1], l[2], l[3]);
    *(float4*)(out_gl + tok * 64 + ec * 8 + 4) = make_float4(l[4], l[5], l[6], l[7]);

    float m = l[0];
    #pragma unroll
    for (int j = 1; j < 8; ++j) m = fmaxf(m, l[j]);
    m = fmaxf(m, __shfl_xor(m, 1));
    m = fmaxf(m, __shfl_xor(m, 2));
    m = fmaxf(m, __shfl_xor(m, 4));

    float s[8], ssum = 0.f;
    #pragma unroll
    for (int j = 0; j < 8; ++j) { s[j] = expf(l[j] - m); ssum += s[j]; }
    ssum += __shfl_xor(ssum, 1);
    ssum += __shfl_xor(ssum, 2);
    ssum += __shfl_xor(ssum, 4);
    const float inv = 1.0f / ssum;
    #pragma unroll
    for (int j = 0; j < 8; ++j) s[j] *= inv;
    *(float4*)(out_gs + tok * 64 + ec * 8)     = make_float4(s[0], s[1], s[2], s[3]);
    *(float4*)(out_gs + tok * 64 + ec * 8 + 4) = make_float4(s[4], s[5], s[6], s[7]);

    // local top-2 over 8 (strict '>' + ascending idx => lowest index wins ties)
    float v1 = s[0], v2 = s[1]; int i1 = ec * 8, i2 = ec * 8 + 1;
    if (s[1] > v1) { v2 = v1; i2 = i1; v1 = s[1]; i1 = ec * 8 + 1; }
    #pragma unroll
    for (int j = 2; j < 8; ++j) {
      if (s[j] > v1)      { v2 = v1; i2 = i1; v1 = s[j]; i1 = ec * 8 + j; }
      else if (s[j] > v2) { v2 = s[j]; i2 = ec * 8 + j; }
    }
    // merge across the 8 expert-lanes (butterfly)
    #pragma unroll
    for (int msk = 1; msk < 8; msk <<= 1) {
      const float w1 = __shfl_xor(v1, msk), w2 = __shfl_xor(v2, msk);
      const int   j1 = __shfl_xor(i1, msk), j2 = __shfl_xor(i2, msk);
      const bool wfirst = (w1 > v1) || (w1 == v1 && j1 < i1);
      if (wfirst) {
        const bool vsec = (v1 > w2) || (v1 == w2 && i1 < j2);
        v2 = vsec ? v1 : w2; i2 = vsec ? i1 : j2;
        v1 = w1; i1 = j1;
      } else {
        const bool wsec = (w1 > v2) || (w1 == v2 && j1 < i2);
        if (wsec) { v2 = w1; i2 = j1; }
      }
    }
    if (ec == 0) {
      *(float2*)(out_tks + tok * 2) = make_float2(v1, v2);
      *(float2*)(out_tki + tok * 2) = make_float2((float)i1, (float)i2);
    }
  }
}

extern "C" void kernel_launch(void* const* d_in, const int* in_sizes, int n_in,
                              void* d_out, int out_size, void* d_ws, size_t ws_size,
                              hipStream_t stream) {
  const float* vis   = (const float*)d_in[0];
  const float* query = (const float*)d_in[1];
  const float* wg    = (const float*)d_in[2];
  float* ws  = (float*)d_ws;
  float* o   = (float*)d_out;
  hipLaunchKernelGGL(prep_kernel, dim3(264), dim3(256), 0, stream, query, wg, ws);
  hipLaunchKernelGGL(router_main, dim3(1152), dim3(64), 0, stream, vis, ws, o);
}

// Round 3
// 495.599 us; speedup vs baseline: 1.2885x; 1.2885x over previous
//
#include <hip/hip_runtime.h>
#include <math.h>

#define HIDDEN 1024

typedef _Float16 half8 __attribute__((ext_vector_type(8)));
typedef float floatx4 __attribute__((ext_vector_type(4)));

// out layout (floats): topk_scores, topk_idx, gate_scores, gate_logits
#define OUT_TKS 0
#define OUT_TKI 147456
#define OUT_GS  294912
#define OUT_GL  5013504

// ws layout: WH = 65536 f16 (128KB) | WL = 65536 f16 (128KB) | QL = 512 f32
// WH/WL are in MFMA B-fragment order: idx = ((c*4+nt)*64 + lane)*8 + j
//   expert e = nt*16 + (lane&15), k = c*32 + (lane>>4)*8 + j
#define QL_FOFF 65536   // float offset of QL (after 65536 f16 *2 arrays = 65536 floats)

// blocks 0..63: split W_vis into f16 hi/lo fragment-ordered arrays
// blocks 64..71: query logits (8 x 64)
__global__ __launch_bounds__(256) void prep_kernel(
    const float* __restrict__ query_emb, const float* __restrict__ W_gate,
    float* __restrict__ ws) {
  const int bid = blockIdx.x, tid = threadIdx.x;
  if (bid < 64) {
    _Float16* WH = (_Float16*)ws;
    _Float16* WL = WH + 65536;
    const int base = (bid * 256 + tid) * 4;
    #pragma unroll
    for (int u = 0; u < 4; ++u) {
      const int idx = base + u;
      const int j  = idx & 7;
      const int L  = (idx >> 3) & 63;
      const int nt = (idx >> 9) & 3;
      const int c  = idx >> 11;
      const int e  = nt * 16 + (L & 15);
      const int k  = c * 32 + (L >> 4) * 8 + j;
      const float w = W_gate[e * 2048 + k];
      const _Float16 hi = (_Float16)w;            // RNE
      const float hif = (float)hi;
      WH[idx] = hi;
      WL[idx] = (_Float16)((w - hif) * 2048.0f);  // scaled: stays normal in f16
    }
  } else {
    const int b = bid - 64;                // 0..7
    const int e = tid >> 2, qq = tid & 3;  // expert, quarter of K
    const float* qp = query_emb + b * 1024 + qq * 256;
    const float* wp = W_gate + e * 2048 + 1024 + qq * 256;
    float s = 0.f;
    #pragma unroll 4
    for (int j = 0; j < 256; j += 4) {
      const float4 a = *(const float4*)(qp + j);
      const float4 w = *(const float4*)(wp + j);
      s += a.x * w.x + a.y * w.y + a.z * w.z + a.w * w.w;
    }
    s += __shfl_xor(s, 1);
    s += __shfl_xor(s, 2);
    if (qq == 0) ws[QL_FOFF + b * 64 + e] = s;
  }
}

// Wave-independent MFMA router: each wave owns 16 tokens x 64 experts.
// No LDS, no barriers. A-fragments loaded straight from global (coalesced
// 128B/row segments); B-fragments from the prearranged L2-resident ws arrays.
// fp32 = f16hi + f16lo*2^-11;  A.B = Ah.Bh + 2^-11*(Ah.Bl' + Al'.Bh)
__global__ __launch_bounds__(256, 3) void router_main(
    const float* __restrict__ vis, const float* __restrict__ ws,
    float* __restrict__ out) {
  const int tid = threadIdx.x;
  const int L  = tid & 63;         // lane
  const int wv = tid >> 6;         // wave in block
  const int m  = L & 15;           // A-frag row / C-frag expert col
  const int q  = L >> 4;           // quad
  const long t0 = (long)blockIdx.x * 64 + wv * 16;
  const _Float16* WH = (const _Float16*)ws;
  const _Float16* WL = WH + 65536;
  const float* QL = ws + QL_FOFF;

  const float* ap = vis + (t0 + m) * HIDDEN + q * 8;
  const int fo = L * 8;            // lane offset into fragment arrays (f16 units)

  floatx4 acc[4], accx[4];
  #pragma unroll
  for (int nt = 0; nt < 4; ++nt) {
    acc[nt]  = (floatx4){0.f, 0.f, 0.f, 0.f};
    accx[nt] = (floatx4){0.f, 0.f, 0.f, 0.f};
  }

  float4 a0 = *(const float4*)ap;
  float4 a1 = *(const float4*)(ap + 4);

  for (int c = 0; c < 32; ++c) {
    // prefetch next chunk's A (c==31: reload same addr, harmless L1 hit)
    const float* apn = ap + ((c < 31) ? 32 : 0);
    const float4 n0 = *(const float4*)apn;
    const float4 n1 = *(const float4*)(apn + 4);

    // split current 8 fp32 -> f16 hi + scaled f16 lo
    half8 ah, al;
    {
      const float av[8] = {a0.x, a0.y, a0.z, a0.w, a1.x, a1.y, a1.z, a1.w};
      #pragma unroll
      for (int j = 0; j < 8; ++j) {
        const _Float16 h = (_Float16)av[j];
        ah[j] = h;
        al[j] = (_Float16)((av[j] - (float)h) * 2048.0f);
      }
    }

    const _Float16* whp = WH + (c * 4) * 512 + fo;
    const _Float16* wlp = WL + (c * 4) * 512 + fo;
    #pragma unroll
    for (int nt = 0; nt < 4; ++nt) {
      const half8 wh = *(const half8*)(whp + nt * 512);
      const half8 wl = *(const half8*)(wlp + nt * 512);
      acc[nt]  = __builtin_amdgcn_mfma_f32_16x16x32_f16(ah, wh, acc[nt],  0, 0, 0);
      accx[nt] = __builtin_amdgcn_mfma_f32_16x16x32_f16(ah, wl, accx[nt], 0, 0, 0);
      accx[nt] = __builtin_amdgcn_mfma_f32_16x16x32_f16(al, wh, accx[nt], 0, 0, 0);
    }

    ap = apn;
    a0 = n0; a1 = n1;
  }

  // ---- epilogue ----
  // C-frag: expert = nt*16 + m, token = t0 + q*4 + reg
  const int bq = blockIdx.x / 144;     // 9216 tokens per query row
  float ql[4];
  #pragma unroll
  for (int nt = 0; nt < 4; ++nt) ql[nt] = QL[bq * 64 + nt * 16 + m];

  float* out_tks = out + OUT_TKS;
  float* out_tki = out + OUT_TKI;
  float* out_gs  = out + OUT_GS;
  float* out_gl  = out + OUT_GL;

  #pragma unroll
  for (int i = 0; i < 4; ++i) {
    const long tok = t0 + q * 4 + i;
    float l[4];
    #pragma unroll
    for (int nt = 0; nt < 4; ++nt)
      l[nt] = acc[nt][i] + accx[nt][i] * (1.0f / 2048.0f) + ql[nt];
    #pragma unroll
    for (int nt = 0; nt < 4; ++nt)
      out_gl[tok * 64 + nt * 16 + m] = l[nt];

    float mx = fmaxf(fmaxf(l[0], l[1]), fmaxf(l[2], l[3]));
    mx = fmaxf(mx, __shfl_xor(mx, 1));
    mx = fmaxf(mx, __shfl_xor(mx, 2));
    mx = fmaxf(mx, __shfl_xor(mx, 4));
    mx = fmaxf(mx, __shfl_xor(mx, 8));

    float s[4], ssum = 0.f;
    #pragma unroll
    for (int nt = 0; nt < 4; ++nt) { s[nt] = expf(l[nt] - mx); ssum += s[nt]; }
    ssum += __shfl_xor(ssum, 1);
    ssum += __shfl_xor(ssum, 2);
    ssum += __shfl_xor(ssum, 4);
    ssum += __shfl_xor(ssum, 8);
    const float inv = 1.0f / ssum;
    #pragma unroll
    for (int nt = 0; nt < 4; ++nt) s[nt] *= inv;
    #pragma unroll
    for (int nt = 0; nt < 4; ++nt)
      out_gs[tok * 64 + nt * 16 + m] = s[nt];

    // local top-2 over the 4 experts this lane owns (ids ascending in nt,
    // strict '>' => lowest index wins ties, jax semantics)
    float v1 = s[0], v2 = s[1]; int i1 = m, i2 = 16 + m;
    if (s[1] > v1) { v2 = v1; i2 = i1; v1 = s[1]; i1 = 16 + m; }
    if (s[2] > v1)      { v2 = v1; i2 = i1; v1 = s[2]; i1 = 32 + m; }
    else if (s[2] > v2) { v2 = s[2]; i2 = 32 + m; }
    if (s[3] > v1)      { v2 = v1; i2 = i1; v1 = s[3]; i1 = 48 + m; }
    else if (s[3] > v2) { v2 = s[3]; i2 = 48 + m; }

    // butterfly merge across the 16-lane group
    #pragma unroll
    for (int msk = 1; msk < 16; msk <<= 1) {
      const float w1 = __shfl_xor(v1, msk), w2 = __shfl_xor(v2, msk);
      const int   j1 = __shfl_xor(i1, msk), j2 = __shfl_xor(i2, msk);
      const bool wfirst = (w1 > v1) || (w1 == v1 && j1 < i1);
      if (wfirst) {
        const bool vsec = (v1 > w2) || (v1 == w2 && i1 < j2);
        v2 = vsec ? v1 : w2; i2 = vsec ? i1 : j2;
        v1 = w1; i1 = j1;
      } else {
        const bool wsec = (w1 > v2) || (w1 == v2 && j1 < i2);
        if (wsec) { v2 = w1; i2 = j1; }
      }
    }
    if (m == 0) {
      *(float2*)(out_tks + tok * 2) = make_float2(v1, v2);
      *(float2*)(out_tki + tok * 2) = make_float2((float)i1, (float)i2);
    }
  }
}

extern "C" void kernel_launch(void* const* d_in, const int* in_sizes, int n_in,
                              void* d_out, int out_size, void* d_ws, size_t ws_size,
                              hipStream_t stream) {
  const float* vis   = (const float*)d_in[0];
  const float* query = (const float*)d_in[1];
  const float* wg    = (const float*)d_in[2];
  float* ws = (float*)d_ws;
  float* o  = (float*)d_out;
  hipLaunchKernelGGL(prep_kernel, dim3(72), dim3(256), 0, stream, query, wg, ws);
  hipLaunchKernelGGL(router_main, dim3(1152), dim3(256), 0, stream, vis, ws, o);
}